// Round 3
// baseline (220.730 us; speedup 1.0000x reference)
//
#include <hip/hip_runtime.h>

// HingeLoss: B=4M rows, 7 classes.
// elem = mask ? |logit - target| : relu(logit - target); out = sum(elem)
// mask[i][j] = (j in repr_num[i][0..2]);  target = (label==1) ? 1 : 0
//
// R3: LDS-staged tiles so ALL global loads are unit-lane-stride float4/int4
// (the only pattern measured at ~6.3 TB/s). Compute phase reads LDS with
// interleaved rows -> conflict-free (bank stride 7, gcd(7,32)=1).

#define NCLS   7
#define T_ROWS 512   // rows per tile; LDS = 512*(28+4+12) B = 22528 B -> 7 blocks/CU

__global__ __launch_bounds__(256) void hinge_sum_kernel(
    const float4* __restrict__ logit4,   // [B*7/4]
    const int4*  __restrict__ label4,    // [B/4]
    const int4*  __restrict__ repr4,     // [B*3/4]
    float* __restrict__ out,             // [1]
    int B, int ntiles)
{
    __shared__ float s_logit[T_ROWS * NCLS]; // 14336 B
    __shared__ int   s_label[T_ROWS];        //  2048 B
    __shared__ int   s_repr [T_ROWS * 3];    //  6144 B

    const int tid = threadIdx.x;
    float acc = 0.0f;

    for (int tile = blockIdx.x; tile < ntiles; tile += gridDim.x) {
        const int row_base = tile * T_ROWS;          // multiple of 512 -> all f4-aligned
        const int rows = min(T_ROWS, B - row_base);

        // ---- stage: unit-lane-stride vector loads ----
        const int nlog4 = (rows * NCLS) / 4;         // 896 (full) / 448 (tail)
        const float4* gl = logit4 + ((size_t)row_base * NCLS) / 4;
        for (int k = tid; k < nlog4; k += 256)
            ((float4*)s_logit)[k] = gl[k];

        const int nlab4 = (rows + 3) / 4;            // 128
        const int4* glb = label4 + row_base / 4;
        for (int k = tid; k < nlab4; k += 256)
            ((int4*)s_label)[k] = glb[k];

        const int nrep4 = (rows * 3) / 4;            // 384
        const int4* grp = repr4 + ((size_t)row_base * 3) / 4;
        for (int k = tid; k < nrep4; k += 256)
            ((int4*)s_repr)[k] = grp[k];

        __syncthreads();

        // ---- compute: interleaved rows (lane l -> row l) -> conflict-free LDS ----
        for (int r = tid; r < rows; r += 256) {
            float tgt = (s_label[r] == 1) ? 1.0f : 0.0f;
            int a = s_repr[3 * r + 0];
            int b = s_repr[3 * r + 1];
            int c = s_repr[3 * r + 2];
            unsigned m = (1u << a) | (1u << b) | (1u << c);
            #pragma unroll
            for (int j = 0; j < NCLS; ++j) {
                float d = s_logit[r * NCLS + j] - tgt;
                acc += ((m >> j) & 1u) ? fabsf(d) : fmaxf(d, 0.0f);
            }
        }

        __syncthreads();  // before next tile overwrites LDS
    }

    // ---- wave (64-lane) butterfly reduce, then one atomic per block ----
    #pragma unroll
    for (int off = 32; off > 0; off >>= 1)
        acc += __shfl_down(acc, off, 64);

    __shared__ float wave_sums[4];
    int lane = threadIdx.x & 63;
    int wid  = threadIdx.x >> 6;
    if (lane == 0) wave_sums[wid] = acc;
    __syncthreads();

    if (tid == 0) {
        float s = wave_sums[0] + wave_sums[1] + wave_sums[2] + wave_sums[3];
        atomicAdd(out, s);
    }
}

extern "C" void kernel_launch(void* const* d_in, const int* in_sizes, int n_in,
                              void* d_out, int out_size, void* d_ws, size_t ws_size,
                              hipStream_t stream) {
    const float4* logit4 = (const float4*)d_in[0];
    const int4*   label4 = (const int4*)d_in[1];
    const int4*   repr4  = (const int4*)d_in[2];
    float*        out    = (float*)d_out;

    int B = in_sizes[1];                       // label is [B]
    int ntiles = (B + T_ROWS - 1) / T_ROWS;    // 7813

    // d_out is re-poisoned to 0xAA before every timed launch — zero it here.
    hipMemsetAsync(out, 0, sizeof(float), stream);

    // 7 blocks/CU resident (22.5 KB LDS each); grid-stride over tiles.
    int threads = 256;
    int blocks  = 1792;
    hinge_sum_kernel<<<blocks, threads, 0, stream>>>(logit4, label4, repr4, out, B, ntiles);
}

// Round 4
// 204.896 us; speedup vs baseline: 1.0773x; 1.0773x over previous
//
#include <hip/hip_runtime.h>

// HingeLoss: B=4M rows, 7 classes.
// elem = mask ? |logit - target| : relu(logit - target); out = sum(elem)
// mask[i][j] = (j in repr_num[i][0..2]);  target = (label==1) ? 1 : 0
//
// R4: remove same-address atomicAdd contention (2048 serialized device-scope
// atomics to one line ~= 40us tail). Each block writes a private partial to
// d_ws; a 1-block kernel reduces the partials into d_out.

#define NCLS 7
#define NBLK 2048

__global__ __launch_bounds__(256) void hinge_partial_kernel(
    const float4* __restrict__ logit4,    // [7*nchunk]
    const int4* __restrict__ label4,      // [nchunk]
    const int4* __restrict__ repr4,       // [3*nchunk]
    float* __restrict__ partials,         // [gridDim.x]
    int nchunk)                           // B/4
{
    int tid = blockIdx.x * blockDim.x + threadIdx.x;
    int stride = gridDim.x * blockDim.x;

    float acc = 0.0f;
    for (int t = tid; t < nchunk; t += stride) {
        float4 L0 = logit4[7 * (size_t)t + 0];
        float4 L1 = logit4[7 * (size_t)t + 1];
        float4 L2 = logit4[7 * (size_t)t + 2];
        float4 L3 = logit4[7 * (size_t)t + 3];
        float4 L4 = logit4[7 * (size_t)t + 4];
        float4 L5 = logit4[7 * (size_t)t + 5];
        float4 L6 = logit4[7 * (size_t)t + 6];

        int4 lab = label4[t];

        int4 r0 = repr4[3 * (size_t)t + 0];
        int4 r1 = repr4[3 * (size_t)t + 1];
        int4 r2 = repr4[3 * (size_t)t + 2];

        unsigned m0 = (1u << r0.x) | (1u << r0.y) | (1u << r0.z);
        unsigned m1 = (1u << r0.w) | (1u << r1.x) | (1u << r1.y);
        unsigned m2 = (1u << r1.z) | (1u << r1.w) | (1u << r2.x);
        unsigned m3 = (1u << r2.y) | (1u << r2.z) | (1u << r2.w);

        float t0 = (lab.x == 1) ? 1.0f : 0.0f;
        float t1 = (lab.y == 1) ? 1.0f : 0.0f;
        float t2 = (lab.z == 1) ? 1.0f : 0.0f;
        float t3 = (lab.w == 1) ? 1.0f : 0.0f;

        float f[28];
        f[0]=L0.x;  f[1]=L0.y;  f[2]=L0.z;  f[3]=L0.w;
        f[4]=L1.x;  f[5]=L1.y;  f[6]=L1.z;  f[7]=L1.w;
        f[8]=L2.x;  f[9]=L2.y;  f[10]=L2.z; f[11]=L2.w;
        f[12]=L3.x; f[13]=L3.y; f[14]=L3.z; f[15]=L3.w;
        f[16]=L4.x; f[17]=L4.y; f[18]=L4.z; f[19]=L4.w;
        f[20]=L5.x; f[21]=L5.y; f[22]=L5.z; f[23]=L5.w;
        f[24]=L6.x; f[25]=L6.y; f[26]=L6.z; f[27]=L6.w;

        float tgt[4] = {t0, t1, t2, t3};
        unsigned mk[4] = {m0, m1, m2, m3};

        #pragma unroll
        for (int k = 0; k < 4; ++k) {
            #pragma unroll
            for (int j = 0; j < NCLS; ++j) {
                float d = f[7 * k + j] - tgt[k];
                acc += ((mk[k] >> j) & 1u) ? fabsf(d) : fmaxf(d, 0.0f);
            }
        }
    }

    // wave (64-lane) butterfly reduce
    #pragma unroll
    for (int off = 32; off > 0; off >>= 1)
        acc += __shfl_down(acc, off, 64);

    __shared__ float wave_sums[4];
    int lane = threadIdx.x & 63;
    int wid  = threadIdx.x >> 6;
    if (lane == 0) wave_sums[wid] = acc;
    __syncthreads();

    // one contention-free store per block (ws slot), no atomics
    if (threadIdx.x == 0)
        partials[blockIdx.x] = wave_sums[0] + wave_sums[1] + wave_sums[2] + wave_sums[3];
}

__global__ __launch_bounds__(256) void reduce_partials_kernel(
    const float* __restrict__ partials, float* __restrict__ out, int n)
{
    float a = 0.0f;
    for (int i = threadIdx.x; i < n; i += 256)
        a += partials[i];

    #pragma unroll
    for (int off = 32; off > 0; off >>= 1)
        a += __shfl_down(a, off, 64);

    __shared__ float wave_sums[4];
    int lane = threadIdx.x & 63;
    int wid  = threadIdx.x >> 6;
    if (lane == 0) wave_sums[wid] = a;
    __syncthreads();

    if (threadIdx.x == 0)
        out[0] = wave_sums[0] + wave_sums[1] + wave_sums[2] + wave_sums[3];
}

extern "C" void kernel_launch(void* const* d_in, const int* in_sizes, int n_in,
                              void* d_out, int out_size, void* d_ws, size_t ws_size,
                              hipStream_t stream) {
    const float4* logit4 = (const float4*)d_in[0];
    const int4*   label4 = (const int4*)d_in[1];
    const int4*   repr4  = (const int4*)d_in[2];
    float*        out    = (float*)d_out;
    float*        partials = (float*)d_ws;   // 2048 floats of the 437 MB ws

    int B = in_sizes[1];      // label is [B]
    int nchunk = B / 4;

    hinge_partial_kernel<<<NBLK, 256, 0, stream>>>(logit4, label4, repr4, partials, nchunk);
    reduce_partials_kernel<<<1, 256, 0, stream>>>(partials, out, NBLK);
}